// Round 15
// baseline (271.733 us; speedup 1.0000x reference)
//
#include <hip/hip_runtime.h>
#include <hip/hip_bf16.h>
#include <hip/hip_fp16.h>

#define T_LEN   16000
#define NB      16
#define NTT     250         // T_LEN / 64 : plane chunk granularity & kP1 tiles
#define NTB     125         // T_LEN / 128: kC / kE 2-tile groups
#define EPSV    1e-8f

typedef _Float16 f16x8 __attribute__((ext_vector_type(8)));
typedef float    f32x4 __attribute__((ext_vector_type(4)));

__device__ __forceinline__ ushort f2h(float f) {
    _Float16 h = (_Float16)f;
    return *(ushort*)&h;
}
__device__ __forceinline__ float f4c(const float4& v, int i) {
    return i == 0 ? v.x : i == 1 ? v.y : i == 2 ? v.z : v.w;
}
__device__ __forceinline__ void gld16(const ushort* g, ushort* l) {
    __builtin_amdgcn_global_load_lds(
        (const __attribute__((address_space(1))) uint*)g,
        (__attribute__((address_space(3))) uint*)l, 16, 0, 0);
}
__device__ __forceinline__ float waveRed64(float v) {
    #pragma unroll
    for (int m = 1; m <= 32; m <<= 1) v += __shfl_xor(v, m, 64);
    return v;
}
__device__ __forceinline__ float4 ntload4(const float* p) {
    f32x4 v = __builtin_nontemporal_load((const f32x4*)p);
    return make_float4(v[0], v[1], v[2], v[3]);
}

__device__ __forceinline__ float blockSum256(float v, float* red)
{
    #pragma unroll
    for (int off = 32; off; off >>= 1) v += __shfl_down(v, off, 64);
    __syncthreads();
    if ((threadIdx.x & 63) == 0) red[threadIdx.x >> 6] = v;
    __syncthreads();
    return red[0] + red[1] + red[2] + red[3];
}

// ---------------------------------------------------------------------------
// kP1F: fused kW1 (blocks 0..255) + kP1 (blocks 256..4255).
// Plane: Xp[b][tt][kc] = 8KB chunk of 64t x 64k fp16; 16B unit (t,u) at
// slot (t*8 + (u^(t&7)))*8 ushorts.
// Hs stride 70 ushorts (35 words === 3 mod 32): write bank (3cq+2jq)%32 and
// read bank (24u + t/2)%32 are both ~2-way (free) vs 4-way at stride 68.
// b32 writes keep 4B alignment for all c.
// ---------------------------------------------------------------------------
__global__ __launch_bounds__(256) void kP1F(
    const float* __restrict__ x, ushort* __restrict__ Xp,
    float* __restrict__ sp, float* __restrict__ qp,
    const float* __restrict__ cue,
    const float* __restrict__ f1g_w, const float* __restrict__ f1g_b,
    const float* __restrict__ f1b_w, const float* __restrict__ f1b_b,
    const float* __restrict__ cds_w,
    float* __restrict__ G1, float* __restrict__ B1, float* __restrict__ CUE2)
{
    const int bid = blockIdx.x;
    if (bid < 256) {
        const int c = bid;
        const int lane = threadIdx.x & 63, w = threadIdx.x >> 6;
        const float4 wg0 = *(const float4*)(f1g_w + c*512 + lane*8);
        const float4 wg1 = *(const float4*)(f1g_w + c*512 + lane*8 + 4);
        const float4 wb0 = *(const float4*)(f1b_w + c*512 + lane*8);
        const float4 wb1 = *(const float4*)(f1b_w + c*512 + lane*8 + 4);
        const float4 wc0 = *(const float4*)(cds_w + c*512 + lane*8);
        const float4 wc1 = *(const float4*)(cds_w + c*512 + lane*8 + 4);
        #pragma unroll
        for (int bb = 0; bb < 4; ++bb) {
            const int b = w*4 + bb;
            const float4 u0 = *(const float4*)(cue + b*512 + lane*8);
            const float4 u1 = *(const float4*)(cue + b*512 + lane*8 + 4);
            float g = 0.f, bt = 0.f, cv = 0.f;
            #pragma unroll
            for (int i = 0; i < 4; ++i) {
                g  = fmaf(f4c(u0,i), f4c(wg0,i), g);  g  = fmaf(f4c(u1,i), f4c(wg1,i), g);
                bt = fmaf(f4c(u0,i), f4c(wb0,i), bt); bt = fmaf(f4c(u1,i), f4c(wb1,i), bt);
                cv = fmaf(f4c(u0,i), f4c(wc0,i), cv); cv = fmaf(f4c(u1,i), f4c(wc1,i), cv);
            }
            g = waveRed64(g); bt = waveRed64(bt); cv = waveRed64(cv);
            if (lane == 0) {
                G1[b*256 + c]   = fmaxf(g + f1g_b[c], 0.f) + 1.f;
                B1[b*256 + c]   = fmaxf(bt + f1b_b[c], 0.f);
                CUE2[b*256 + c] = fmaxf(cv, 0.f);
            }
        }
        return;
    }

    const int pb = bid - 256;
    const int b = pb / NTT, tt = pb % NTT;
    const int t0 = tt * 64;
    const int tid = threadIdx.x;
    const int cq = tid >> 2, jq = tid & 3;
    __shared__ __align__(16) ushort Hs[256][70];

    #pragma unroll
    for (int cc = 0; cc < 4; ++cc) {
        const int c = cc*64 + cq;
        float s4 = 0.f, q4 = 0.f;
        #pragma unroll
        for (int i = 0; i < 4; ++i) {
            const int ts = (jq + i*4)*4;
            const float4 v = ntload4(x + ((size_t)(b*256 + c))*T_LEN + t0 + ts);
            s4 += v.x + v.y + v.z + v.w;
            q4 += v.x*v.x + v.y*v.y + v.z*v.z + v.w*v.w;
            const ushort h0 = f2h(v.x), h1 = f2h(v.y), h2 = f2h(v.z), h3 = f2h(v.w);
            const uint p0 = (uint)h0 | ((uint)h1 << 16);
            const uint p1 = (uint)h2 | ((uint)h3 << 16);
            *(uint*)&Hs[c][ts]     = p0;
            *(uint*)&Hs[c][ts + 2] = p1;
        }
        s4 += __shfl_xor(s4, 1, 4); s4 += __shfl_xor(s4, 2, 4);
        q4 += __shfl_xor(q4, 1, 4); q4 += __shfl_xor(q4, 2, 4);
        if (jq == 0) {
            sp[((size_t)b*NTT + tt)*256 + c] = s4;
            qp[((size_t)b*NTT + tt)*256 + c] = q4;
        }
    }
    __syncthreads();
    ushort* dst = Xp + ((size_t)(b*NTT + tt)*4)*4096;
    #pragma unroll
    for (int k = 0; k < 8; ++k) {
        const int d  = tid + k*256;
        const int kc = d >> 9, r = d & 511;
        const int t  = r >> 3, us = r & 7;
        const int u  = us ^ (t & 7);
        const int c0 = kc*64 + u*8;
        uint4 val;
        val.x = (uint)Hs[c0+0][t] | ((uint)Hs[c0+1][t] << 16);
        val.y = (uint)Hs[c0+2][t] | ((uint)Hs[c0+3][t] << 16);
        val.z = (uint)Hs[c0+4][t] | ((uint)Hs[c0+5][t] << 16);
        val.w = (uint)Hs[c0+6][t] | ((uint)Hs[c0+7][t] << 16);
        *(uint4*)(dst + (size_t)d*8) = val;
    }
}

// ---------------------------------------------------------------------------
// kR: wide pre-reduce of sp/qp -> s1/q1.  grid (8 cg, 16 b) x 256 thr.
// ---------------------------------------------------------------------------
__global__ __launch_bounds__(256) void kR_reduce(
    const float* __restrict__ sp, const float* __restrict__ qp,
    float* __restrict__ s1, float* __restrict__ q1)
{
    const int cg = blockIdx.x, b = blockIdx.y;
    const int ci = threadIdx.x & 31, ig = threadIdx.x >> 5;   // ig 0..7
    const int c = cg*32 + ci;
    float s = 0.f, q = 0.f;
    for (int i = ig; i < NTT; i += 8) {
        s += sp[((size_t)b*NTT + i)*256 + c];
        q += qp[((size_t)b*NTT + i)*256 + c];
    }
    __shared__ float rs[8][32], rq[8][32];
    rs[ig][ci] = s; rq[ig][ci] = q;
    __syncthreads();
    if (threadIdx.x < 32) {
        float ss = 0.f, qq = 0.f;
        #pragma unroll
        for (int g = 0; g < 8; ++g) { ss += rs[g][threadIdx.x]; qq += rq[g][threadIdx.x]; }
        s1[b*256 + cg*32 + threadIdx.x] = ss;
        q1[b*256 + cg*32 + threadIdx.x] = qq;
    }
}

// ---------------------------------------------------------------------------
// kM2F (stats folded in): each (og,b) block recomputes the per-batch stats
// chain from s1/q1, then G2/E/Msf for its 16-o slice.  grid (8, 16) x 256.
// ---------------------------------------------------------------------------
__global__ __launch_bounds__(256) void kM2F(
    const float* __restrict__ s1, const float* __restrict__ q1,
    const float* __restrict__ gn_a_w, const float* __restrict__ gn_a_b,
    const float* __restrict__ gn_n_w, const float* __restrict__ gn_n_b,
    const float* __restrict__ G1, const float* __restrict__ B1,
    const float* __restrict__ ln1_w, const float* __restrict__ ln1_b,
    const float* __restrict__ CUE2,
    const float* __restrict__ f2g_w, const float* __restrict__ f2g_b,
    const float* __restrict__ f2b_w, const float* __restrict__ f2b_b,
    const float* __restrict__ conv1_w,
    float* __restrict__ a4o, float* __restrict__ G2,
    float* __restrict__ E, ushort* __restrict__ Msf)
{
    const int og = blockIdx.x, b = blockIdx.y;
    const int c = threadIdx.x;
    __shared__ float red[4];
    __shared__ float sc2[256], sa4[256], sd4[256], sg2[16];

    const float sc = s1[b*256 + c];
    const float qc = q1[b*256 + c];

    const float Ninv = 1.f / (256.f * 16000.f);
    const float Tf = 16000.f;

    float S  = blockSum256(sc, red);
    float Q  = blockSum256(qc, red);
    float mu1 = S * Ninv;
    float var1 = Q * Ninv - mu1 * mu1;
    float r1 = rsqrtf(var1 + EPSV);
    float a1 = gn_a_w[c] * r1;
    float d1 = gn_a_b[c] - mu1 * r1 * gn_a_w[c];

    float S2 = blockSum256(a1*sc + Tf*d1, red);
    float Q2 = blockSum256(a1*a1*qc + 2.f*a1*d1*sc + Tf*d1*d1, red);
    float mu2 = S2 * Ninv;
    float var2 = Q2 * Ninv - mu2 * mu2;
    float r2 = rsqrtf(var2 + EPSV);
    float wn = gn_n_w[c];
    float a2 = wn * r2 * a1;
    float d2 = wn * r2 * (d1 - mu2) + gn_n_b[c];

    const float g1v = G1[b*256 + c];
    const float b1v = B1[b*256 + c];
    float a3 = g1v * a2;
    float d3 = g1v * d2 + b1v;

    float S3 = blockSum256(a3*sc + Tf*d3, red);
    float Q3 = blockSum256(a3*a3*qc + 2.f*a3*d3*sc + Tf*d3*d3, red);
    float mu3 = S3 * Ninv;
    float var3 = Q3 * Ninv - mu3 * mu3;
    float r3 = rsqrtf(var3 + EPSV);
    float w1 = ln1_w[c];
    const float a4v = w1 * r3 * a3;
    const float d4v = w1 * r3 * (d3 - mu3) + ln1_b[c];
    sa4[c] = a4v;
    sd4[c] = d4v;
    if (og == 0) a4o[b*256 + c] = a4v;
    sc2[c] = CUE2[b*256 + c];
    __syncthreads();

    const int oi = c >> 4, l16 = c & 15;
    const int o = og*16 + oi;
    float g = 0.f, bt = 0.f, ed = 0.f;
    #pragma unroll
    for (int q = 0; q < 4; ++q) {
        const int k0 = l16*16 + q*4;
        const float4 a  = *(const float4*)(f2g_w  + o*256 + k0);
        const float4 bb = *(const float4*)(f2b_w  + o*256 + k0);
        const float4 cc = *(const float4*)(conv1_w + o*256 + k0);
        const float4 u  = *(const float4*)(&sc2[k0]);
        const float4 dd = *(const float4*)(&sd4[k0]);
        #pragma unroll
        for (int i = 0; i < 4; ++i) {
            g  = fmaf(f4c(u,i),  f4c(a,i),  g);
            bt = fmaf(f4c(u,i),  f4c(bb,i), bt);
            ed = fmaf(f4c(dd,i), f4c(cc,i), ed);
        }
    }
    #pragma unroll
    for (int m = 1; m <= 8; m <<= 1) {
        g  += __shfl_xor(g, m, 16);
        bt += __shfl_xor(bt, m, 16);
        ed += __shfl_xor(ed, m, 16);
    }
    if (l16 == 0) {
        const float G2v = fmaxf(g + f2g_b[o], 0.f) + 1.f;
        const float B2v = fmaxf(bt + f2b_b[o], 0.f);
        G2[b*128 + o] = G2v;
        E[b*128 + o]  = G2v * ed + B2v;
        sg2[oi] = G2v;
    }
    __syncthreads();
    const float av = sa4[c];
    #pragma unroll
    for (int i = 0; i < 16; ++i) {
        const int oo = og*16 + i;
        Msf[((size_t)b*128 + oo)*256 + c] = f2h(sg2[i] * conv1_w[oo*256 + c] * av);
    }
}

// ---------------------------------------------------------------------------
// Kernel C: sumsq GEMM (D=[t][o]).  4 waves = 4 o-strips of 32, TWO 64t
// tiles double-buffered; M fragments + E hoisted.  grid (125, 16).
// ---------------------------------------------------------------------------
__global__ __launch_bounds__(256) void kC_gemm(
    const ushort* __restrict__ Xp, const ushort* __restrict__ Msf,
    const float* __restrict__ E,
    float* __restrict__ q2p)
{
    const int tp = blockIdx.x, b = blockIdx.y;
    const int tid = threadIdx.x, lane = tid & 63, w = tid >> 6;
    const int sub = lane >> 4, li = lane & 15;
    const int o0 = w * 32;
    __shared__ __align__(16) ushort Bs[2][16384]; // 2 x 32 KB

    const ushort* mp = Msf + (size_t)b*32768;

    f16x8 mf[8][2];
    #pragma unroll
    for (int ks = 0; ks < 8; ++ks) {
        const int k8 = (ks >> 1)*64 + (ks & 1)*32 + 8*sub;
        #pragma unroll
        for (int fo = 0; fo < 2; ++fo)
            mf[ks][fo] = *(const f16x8*)(mp + (size_t)(o0 + fo*16 + li)*256 + k8);
    }
    float ev[2];
    #pragma unroll
    for (int fo = 0; fo < 2; ++fo)
        ev[fo] = E[b*128 + o0 + fo*16 + li];

    const ushort* src0 = Xp + ((size_t)(b*NTT + 2*tp)*4)*4096;

    #pragma unroll
    for (int m = 0; m < 8; ++m) {
        const int off = m*2048 + w*512;
        gld16(src0 + off + lane*8, &Bs[0][off]);
    }
    __syncthreads();

    float qv[2] = {0.f, 0.f};
    #pragma unroll
    for (int tile = 0; tile < 2; ++tile) {
        if (tile == 0) {
            const ushort* src1 = src0 + 16384;
            #pragma unroll
            for (int m = 0; m < 8; ++m) {
                const int off = m*2048 + w*512;
                gld16(src1 + off + lane*8, &Bs[1][off]);
            }
        }
        f32x4 acc[4][2];
        #pragma unroll
        for (int i = 0; i < 4; ++i)
            #pragma unroll
            for (int jx = 0; jx < 2; ++jx) acc[i][jx] = (f32x4){0.f,0.f,0.f,0.f};

        #pragma unroll
        for (int ks = 0; ks < 8; ++ks) {
            const int kc = ks >> 1;
            const int uo = (ks & 1)*4 + sub;
            f16x8 xf[4];
            #pragma unroll
            for (int ft = 0; ft < 4; ++ft) {
                const int tl = ft*16 + li;
                xf[ft] = *(const f16x8*)&Bs[tile][kc*4096 + tl*64 + (uo ^ (tl & 7))*8];
            }
            #pragma unroll
            for (int fo = 0; fo < 2; ++fo)
                #pragma unroll
                for (int ft = 0; ft < 4; ++ft)
                    acc[ft][fo] = __builtin_amdgcn_mfma_f32_16x16x32_f16(xf[ft], mf[ks][fo], acc[ft][fo], 0, 0, 0);
        }

        #pragma unroll
        for (int fo = 0; fo < 2; ++fo)
            #pragma unroll
            for (int ft = 0; ft < 4; ++ft)
                #pragma unroll
                for (int r = 0; r < 4; ++r) {
                    const float z = acc[ft][fo][r] + ev[fo];
                    qv[fo] += z*z;
                }
        if (tile == 0) __syncthreads();
    }

    #pragma unroll
    for (int fo = 0; fo < 2; ++fo) {
        float q = qv[fo];
        q += __shfl_xor(q, 16, 64);
        q += __shfl_xor(q, 32, 64);
        if (sub == 0)
            q2p[((size_t)b*NTB + tp)*128 + o0 + fo*16 + li] = q;
    }
}

// ---------------------------------------------------------------------------
// Kernel D2: analytic s2 + q2p reduce -> A2/AE (LDS), then
// F = [conv2*diag(A2*G2)*conv1]*diag(a4) (fp16), h = conv2.AE.
// grid (8 pg, 16 b) x 256 thr.
// ---------------------------------------------------------------------------
__global__ __launch_bounds__(256) void kD2_buildF(
    const float* __restrict__ q2p,
    const float* __restrict__ ln2_w, const float* __restrict__ ln2_b,
    const float* __restrict__ Ev,
    const float* __restrict__ a4, const float* __restrict__ G2,
    const float* __restrict__ s1,
    const float* __restrict__ conv1_w, const float* __restrict__ conv2_w,
    ushort* __restrict__ Fsf, float* __restrict__ h)
{
    const int b = blockIdx.y, pg = blockIdx.x;
    const int tid = threadIdx.x;
    __shared__ float Qs[32][128];
    __shared__ float sA2[128], sAE[128], sAS[256];
    __shared__ float rS[2], rQ[2];

    sAS[tid] = a4[b*256 + tid] * s1[b*256 + tid];
    __syncthreads();

    float s2v = 0.f, qq = 0.f;
    if (tid < 128) {
        float dot = 0.f;
        #pragma unroll 4
        for (int c4 = 0; c4 < 64; ++c4) {
            const float4 cw = *(const float4*)(conv1_w + tid*256 + c4*4);
            const float4 as = *(const float4*)(&sAS[c4*4]);
            dot = fmaf(cw.x, as.x, dot); dot = fmaf(cw.y, as.y, dot);
            dot = fmaf(cw.z, as.z, dot); dot = fmaf(cw.w, as.w, dot);
        }
        s2v = G2[b*128 + tid] * dot + 16000.f * Ev[b*128 + tid];
        for (int tb = 0; tb < NTB; ++tb)
            qq += q2p[((size_t)b*NTB + tb)*128 + tid];
        float S = s2v, Q = qq;
        #pragma unroll
        for (int off = 32; off; off >>= 1) {
            S += __shfl_down(S, off, 64);
            Q += __shfl_down(Q, off, 64);
        }
        if ((tid & 63) == 0) { rS[tid >> 6] = S; rQ[tid >> 6] = Q; }
    }
    __syncthreads();
    const float N2inv = 1.f / (128.f * 16000.f);
    const float mu  = (rS[0] + rS[1]) * N2inv;
    const float var = (rQ[0] + rQ[1]) * N2inv - mu * mu;
    const float r = rsqrtf(var + EPSV);
    if (tid < 128) {
        const float a2v = ln2_w[tid] * r;
        const float d2v = ln2_b[tid] - mu * ln2_w[tid] * r;
        sA2[tid] = a2v;
        sAE[tid] = a2v * Ev[b*128 + tid] + d2v;
    }
    __syncthreads();

    #pragma unroll
    for (int k = 0; k < 16; ++k) {
        const int idx = tid + k*256;
        const int p = idx >> 7, o = idx & 127;
        Qs[p][o] = conv2_w[(pg*32 + p)*128 + o] * sA2[o] * G2[b*128 + o];
    }
    __syncthreads();
    float acc[32];
    #pragma unroll
    for (int p = 0; p < 32; ++p) acc[p] = 0.f;
    for (int o = 0; o < 128; ++o) {
        const float mv = conv1_w[o*256 + tid];
        #pragma unroll
        for (int p = 0; p < 32; ++p) acc[p] = fmaf(Qs[p][o], mv, acc[p]);
    }
    const float a = a4[b*256 + tid];
    #pragma unroll
    for (int p = 0; p < 32; ++p) {
        const size_t idx = ((size_t)b*256 + pg*32 + p)*256 + tid;
        Fsf[idx] = f2h(acc[p] * a);
    }
    if (tid < 32) {
        const int p = pg*32 + tid;
        float hv = 0.f;
        for (int o = 0; o < 128; ++o)
            hv += conv2_w[p*128 + o] * sAE[o];
        h[b*256 + p] = hv;
    }
}

// ---------------------------------------------------------------------------
// Kernel E: out = F x + h (D=[t][o]).  Block 128o, TWO 64-t tiles with
// double-buffered staging; F fragments hoisted to VGPRs.
// grid (125, 32): b=y>>1, obase=(y&1)*128.
// ---------------------------------------------------------------------------
__global__ __launch_bounds__(256) void kE_gemm(
    const ushort* __restrict__ Xp, const ushort* __restrict__ Fsf,
    const float* __restrict__ h, float* __restrict__ out)
{
    const int txp = blockIdx.x;
    const int b = blockIdx.y >> 1;
    const int o_base = (blockIdx.y & 1) * 128;
    const int tid = threadIdx.x, lane = tid & 63, w = tid >> 6;
    const int sub = lane >> 4, li = lane & 15;
    const int o0 = o_base + w * 32;
    __shared__ __align__(16) ushort Bs[2][16384]; // 2 x 32 KB

    const ushort* fp = Fsf + (size_t)b*65536;

    f16x8 ff[8][2];
    #pragma unroll
    for (int ks = 0; ks < 8; ++ks) {
        const int k8 = (ks >> 1)*64 + (ks & 1)*32 + 8*sub;
        #pragma unroll
        for (int fo = 0; fo < 2; ++fo)
            ff[ks][fo] = *(const f16x8*)(fp + (size_t)(o0 + fo*16 + li)*256 + k8);
    }
    float hv[2];
    #pragma unroll
    for (int fo = 0; fo < 2; ++fo)
        hv[fo] = h[b*256 + o0 + fo*16 + li];

    const ushort* src0 = Xp + ((size_t)(b*NTT + 2*txp)*4)*4096;

    #pragma unroll
    for (int m = 0; m < 8; ++m) {
        const int off = m*2048 + w*512;
        gld16(src0 + off + lane*8, &Bs[0][off]);
    }
    __syncthreads();

    #pragma unroll
    for (int tile = 0; tile < 2; ++tile) {
        if (tile == 0) {
            const ushort* src1 = src0 + 16384;
            #pragma unroll
            for (int m = 0; m < 8; ++m) {
                const int off = m*2048 + w*512;
                gld16(src1 + off + lane*8, &Bs[1][off]);
            }
        }
        f32x4 acc[4][2];
        #pragma unroll
        for (int i = 0; i < 4; ++i)
            #pragma unroll
            for (int jx = 0; jx < 2; ++jx) acc[i][jx] = (f32x4){0.f,0.f,0.f,0.f};

        #pragma unroll
        for (int ks = 0; ks < 8; ++ks) {
            const int kc = ks >> 1;
            const int uo = (ks & 1)*4 + sub;
            f16x8 xf[4];
            #pragma unroll
            for (int ft = 0; ft < 4; ++ft) {
                const int tl = ft*16 + li;
                xf[ft] = *(const f16x8*)&Bs[tile][kc*4096 + tl*64 + (uo ^ (tl & 7))*8];
            }
            #pragma unroll
            for (int fo = 0; fo < 2; ++fo)
                #pragma unroll
                for (int ft = 0; ft < 4; ++ft)
                    acc[ft][fo] = __builtin_amdgcn_mfma_f32_16x16x32_f16(xf[ft], ff[ks][fo], acc[ft][fo], 0, 0, 0);
        }

        const int t0 = (2*txp + tile)*64;
        #pragma unroll
        for (int fo = 0; fo < 2; ++fo) {
            const int o = o0 + fo*16 + li;
            float* obase = out + ((size_t)(b*256 + o))*T_LEN + t0;
            #pragma unroll
            for (int ft = 0; ft < 4; ++ft) {
                f32x4 v;
                v[0] = acc[ft][fo][0] + hv[fo];
                v[1] = acc[ft][fo][1] + hv[fo];
                v[2] = acc[ft][fo][2] + hv[fo];
                v[3] = acc[ft][fo][3] + hv[fo];
                __builtin_nontemporal_store(v, (f32x4*)(obase + ft*16 + sub*4));
            }
        }
        if (tile == 0) __syncthreads();
    }
}

// ---------------------------------------------------------------------------
extern "C" void kernel_launch(void* const* d_in, const int* in_sizes, int n_in,
                              void* d_out, int out_size, void* d_ws, size_t ws_size,
                              hipStream_t stream)
{
    const float* x       = (const float*)d_in[0];
    const float* cue     = (const float*)d_in[1];
    const float* gn_a_w  = (const float*)d_in[2];
    const float* gn_a_b  = (const float*)d_in[3];
    const float* gn_n_w  = (const float*)d_in[4];
    const float* gn_n_b  = (const float*)d_in[5];
    const float* f1g_w   = (const float*)d_in[6];
    const float* f1g_b   = (const float*)d_in[7];
    const float* f1b_w   = (const float*)d_in[8];
    const float* f1b_b   = (const float*)d_in[9];
    const float* ln1_w   = (const float*)d_in[10];
    const float* ln1_b   = (const float*)d_in[11];
    const float* conv1_w = (const float*)d_in[12];
    const float* cds_w   = (const float*)d_in[13];
    const float* f2g_w   = (const float*)d_in[14];
    const float* f2g_b   = (const float*)d_in[15];
    const float* f2b_w   = (const float*)d_in[16];
    const float* f2b_b   = (const float*)d_in[17];
    const float* ln2_w   = (const float*)d_in[18];
    const float* ln2_b   = (const float*)d_in[19];
    const float* conv2_w = (const float*)d_in[20];
    float* out = (float*)d_out;

    float* ws = (float*)d_ws;
    float*  sp   = ws;                       // 1,024,000
    float*  qp   = ws + 1024000;             // 1,024,000
    float*  G1   = ws + 2048000;             // 4,096
    float*  B1   = ws + 2052096;             // 4,096
    float*  CUE2 = ws + 2056192;             // 4,096
    float*  G2   = ws + 2060288;             // 2,048
    float*  a4   = ws + 2062336;             // 4,096
    float*  E    = ws + 2066432;             // 2,048
    float*  h    = ws + 2068480;             // 4,096
    float*  s1   = ws + 2072576;             // 4,096
    float*  q1   = ws + 2076672;             // 4,096
    float*  q2p  = ws + 2080768;             // 256,000
    ushort* Msf  = (ushort*)(ws + 2336768);  // 524,288 ush (262,144 f)
    ushort* Fsf  = (ushort*)(ws + 2598912);  // 1,048,576 ush (524,288 f)
    ushort* Xp   = (ushort*)(ws + 3123200);  // 65,536,000 ush
    // total ~ 35,891,200 floats ~= 143.6 MB

    kP1F<<<256 + NTT*NB, 256, 0, stream>>>(x, Xp, sp, qp,
        cue, f1g_w, f1g_b, f1b_w, f1b_b, cds_w, G1, B1, CUE2);

    kR_reduce<<<dim3(8, NB), 256, 0, stream>>>(sp, qp, s1, q1);

    kM2F<<<dim3(8, NB), 256, 0, stream>>>(s1, q1,
        gn_a_w, gn_a_b, gn_n_w, gn_n_b, G1, B1, ln1_w, ln1_b,
        CUE2, f2g_w, f2g_b, f2b_w, f2b_b, conv1_w,
        a4, G2, E, Msf);

    kC_gemm<<<dim3(NTB, NB), 256, 0, stream>>>(Xp, Msf, E, q2p);

    kD2_buildF<<<dim3(8, NB), 256, 0, stream>>>(q2p, ln2_w, ln2_b, E,
                                                a4, G2, s1, conv1_w, conv2_w,
                                                Fsf, h);

    kE_gemm<<<dim3(NTB, NB*2), 256, 0, stream>>>(Xp, Fsf, h, out);
}

// Round 16
// 264.648 us; speedup vs baseline: 1.0268x; 1.0268x over previous
//
#include <hip/hip_runtime.h>
#include <hip/hip_bf16.h>
#include <hip/hip_fp16.h>

#define T_LEN   16000
#define NB      16
#define NTT     250         // T_LEN / 64 : plane chunk granularity & kP1 tiles
#define NTB     125         // T_LEN / 128: kC / kE 2-tile groups
#define EPSV    1e-8f

typedef _Float16 f16x8 __attribute__((ext_vector_type(8)));
typedef float    f32x4 __attribute__((ext_vector_type(4)));

__device__ __forceinline__ ushort f2h(float f) {
    _Float16 h = (_Float16)f;
    return *(ushort*)&h;
}
__device__ __forceinline__ float f4c(const float4& v, int i) {
    return i == 0 ? v.x : i == 1 ? v.y : i == 2 ? v.z : v.w;
}
__device__ __forceinline__ void gld16(const ushort* g, ushort* l) {
    __builtin_amdgcn_global_load_lds(
        (const __attribute__((address_space(1))) uint*)g,
        (__attribute__((address_space(3))) uint*)l, 16, 0, 0);
}
__device__ __forceinline__ float waveRed64(float v) {
    #pragma unroll
    for (int m = 1; m <= 32; m <<= 1) v += __shfl_xor(v, m, 64);
    return v;
}
__device__ __forceinline__ float4 ntload4(const float* p) {
    f32x4 v = __builtin_nontemporal_load((const f32x4*)p);
    return make_float4(v[0], v[1], v[2], v[3]);
}

__device__ __forceinline__ float blockSum256(float v, float* red)
{
    #pragma unroll
    for (int off = 32; off; off >>= 1) v += __shfl_down(v, off, 64);
    __syncthreads();
    if ((threadIdx.x & 63) == 0) red[threadIdx.x >> 6] = v;
    __syncthreads();
    return red[0] + red[1] + red[2] + red[3];
}

// ---------------------------------------------------------------------------
// kP1F: fused kW1 (blocks 0..255) + kP1 (blocks 256..4255), LDS-free.
// Plane: Xp[b][tt][kc] = 8KB chunk of 64t x 64k fp16; 16B unit (t,u) at
// slot (t*8 + (u^(t&7)))*8 ushorts.
// Tile body: thread (oct=tid>>3, j=tid&7) owns channels oct*8..+7 and
// t-values {j*4..j*4+3, 32+j*4..+3}; transpose done in registers, units
// stored directly to global (no LDS, no barrier).
// ---------------------------------------------------------------------------
__global__ __launch_bounds__(256) void kP1F(
    const float* __restrict__ x, ushort* __restrict__ Xp,
    float* __restrict__ sp, float* __restrict__ qp,
    const float* __restrict__ cue,
    const float* __restrict__ f1g_w, const float* __restrict__ f1g_b,
    const float* __restrict__ f1b_w, const float* __restrict__ f1b_b,
    const float* __restrict__ cds_w,
    float* __restrict__ G1, float* __restrict__ B1, float* __restrict__ CUE2)
{
    const int bid = blockIdx.x;
    const int tid = threadIdx.x;
    if (bid < 256) {
        const int c = bid;
        const int lane = tid & 63, w = tid >> 6;
        const float4 wg0 = *(const float4*)(f1g_w + c*512 + lane*8);
        const float4 wg1 = *(const float4*)(f1g_w + c*512 + lane*8 + 4);
        const float4 wb0 = *(const float4*)(f1b_w + c*512 + lane*8);
        const float4 wb1 = *(const float4*)(f1b_w + c*512 + lane*8 + 4);
        const float4 wc0 = *(const float4*)(cds_w + c*512 + lane*8);
        const float4 wc1 = *(const float4*)(cds_w + c*512 + lane*8 + 4);
        #pragma unroll
        for (int bb = 0; bb < 4; ++bb) {
            const int b = w*4 + bb;
            const float4 u0 = *(const float4*)(cue + b*512 + lane*8);
            const float4 u1 = *(const float4*)(cue + b*512 + lane*8 + 4);
            float g = 0.f, bt = 0.f, cv = 0.f;
            #pragma unroll
            for (int i = 0; i < 4; ++i) {
                g  = fmaf(f4c(u0,i), f4c(wg0,i), g);  g  = fmaf(f4c(u1,i), f4c(wg1,i), g);
                bt = fmaf(f4c(u0,i), f4c(wb0,i), bt); bt = fmaf(f4c(u1,i), f4c(wb1,i), bt);
                cv = fmaf(f4c(u0,i), f4c(wc0,i), cv); cv = fmaf(f4c(u1,i), f4c(wc1,i), cv);
            }
            g = waveRed64(g); bt = waveRed64(bt); cv = waveRed64(cv);
            if (lane == 0) {
                G1[b*256 + c]   = fmaxf(g + f1g_b[c], 0.f) + 1.f;
                B1[b*256 + c]   = fmaxf(bt + f1b_b[c], 0.f);
                CUE2[b*256 + c] = fmaxf(cv, 0.f);
            }
        }
        return;
    }

    // ---- tile body (register-only transpose) ----
    const int pb = bid - 256;
    const int b = pb / NTT, tt = pb % NTT;
    const int t0 = tt * 64;
    const int oct = tid >> 3, j = tid & 7;       // oct 0..31, j 0..7

    const float* xb = x + ((size_t)(b*256 + oct*8))*T_LEN + t0;

    float s_[8], q_[8];
    uint uA[4][4], uB[4][4];                     // [k][pair]: unit words

    #pragma unroll
    for (int i = 0; i < 8; ++i) {
        const float4 vA = ntload4(xb + (size_t)i*T_LEN + j*4);
        const float4 vB = ntload4(xb + (size_t)i*T_LEN + 32 + j*4);
        float s4 = vA.x + vA.y + vA.z + vA.w + vB.x + vB.y + vB.z + vB.w;
        float q4 = vA.x*vA.x + vA.y*vA.y + vA.z*vA.z + vA.w*vA.w
                 + vB.x*vB.x + vB.y*vB.y + vB.z*vB.z + vB.w*vB.w;
        s_[i] = s4; q_[i] = q4;
        #pragma unroll
        for (int k = 0; k < 4; ++k) {
            const ushort ha = f2h(f4c(vA, k));
            const ushort hb = f2h(f4c(vB, k));
            if (i & 1) {
                uA[k][i >> 1] |= ((uint)ha << 16);
                uB[k][i >> 1] |= ((uint)hb << 16);
            } else {
                uA[k][i >> 1] = (uint)ha;
                uB[k][i >> 1] = (uint)hb;
            }
        }
    }

    // direct global stores of 16B units (swizzled slots, full 128B windows)
    ushort* dst = Xp + ((size_t)(b*NTT + tt)*4 + (oct >> 3))*4096;
    const int u = oct & 7;
    #pragma unroll
    for (int k = 0; k < 4; ++k) {
        const int tA = j*4 + k;
        const int tB = 32 + j*4 + k;
        uint4 wa, wb;
        wa.x = uA[k][0]; wa.y = uA[k][1]; wa.z = uA[k][2]; wa.w = uA[k][3];
        wb.x = uB[k][0]; wb.y = uB[k][1]; wb.z = uB[k][2]; wb.w = uB[k][3];
        *(uint4*)(dst + (size_t)(tA*8 + (u ^ (tA & 7)))*8) = wa;
        *(uint4*)(dst + (size_t)(tB*8 + (u ^ (tB & 7)))*8) = wb;
    }

    // s/q partials: reduce over the 8-lane j-group per channel
    #pragma unroll
    for (int i = 0; i < 8; ++i) {
        s_[i] += __shfl_xor(s_[i], 1, 8);
        s_[i] += __shfl_xor(s_[i], 2, 8);
        s_[i] += __shfl_xor(s_[i], 4, 8);
        q_[i] += __shfl_xor(q_[i], 1, 8);
        q_[i] += __shfl_xor(q_[i], 2, 8);
        q_[i] += __shfl_xor(q_[i], 4, 8);
    }
    if (j == 0) {
        float* spb = sp + ((size_t)b*NTT + tt)*256 + oct*8;
        float* qpb = qp + ((size_t)b*NTT + tt)*256 + oct*8;
        *(float4*)(spb)     = make_float4(s_[0], s_[1], s_[2], s_[3]);
        *(float4*)(spb + 4) = make_float4(s_[4], s_[5], s_[6], s_[7]);
        *(float4*)(qpb)     = make_float4(q_[0], q_[1], q_[2], q_[3]);
        *(float4*)(qpb + 4) = make_float4(q_[4], q_[5], q_[6], q_[7]);
    }
}

// ---------------------------------------------------------------------------
// kR: wide pre-reduce of sp/qp -> s1/q1.  grid (8 cg, 16 b) x 256 thr.
// ---------------------------------------------------------------------------
__global__ __launch_bounds__(256) void kR_reduce(
    const float* __restrict__ sp, const float* __restrict__ qp,
    float* __restrict__ s1, float* __restrict__ q1)
{
    const int cg = blockIdx.x, b = blockIdx.y;
    const int ci = threadIdx.x & 31, ig = threadIdx.x >> 5;   // ig 0..7
    const int c = cg*32 + ci;
    float s = 0.f, q = 0.f;
    for (int i = ig; i < NTT; i += 8) {
        s += sp[((size_t)b*NTT + i)*256 + c];
        q += qp[((size_t)b*NTT + i)*256 + c];
    }
    __shared__ float rs[8][32], rq[8][32];
    rs[ig][ci] = s; rq[ig][ci] = q;
    __syncthreads();
    if (threadIdx.x < 32) {
        float ss = 0.f, qq = 0.f;
        #pragma unroll
        for (int g = 0; g < 8; ++g) { ss += rs[g][threadIdx.x]; qq += rq[g][threadIdx.x]; }
        s1[b*256 + cg*32 + threadIdx.x] = ss;
        q1[b*256 + cg*32 + threadIdx.x] = qq;
    }
}

// ---------------------------------------------------------------------------
// kM2F (stats folded in): each (og,b) block recomputes the per-batch stats
// chain from s1/q1, then G2/E/Msf for its 16-o slice.  grid (8, 16) x 256.
// ---------------------------------------------------------------------------
__global__ __launch_bounds__(256) void kM2F(
    const float* __restrict__ s1, const float* __restrict__ q1,
    const float* __restrict__ gn_a_w, const float* __restrict__ gn_a_b,
    const float* __restrict__ gn_n_w, const float* __restrict__ gn_n_b,
    const float* __restrict__ G1, const float* __restrict__ B1,
    const float* __restrict__ ln1_w, const float* __restrict__ ln1_b,
    const float* __restrict__ CUE2,
    const float* __restrict__ f2g_w, const float* __restrict__ f2g_b,
    const float* __restrict__ f2b_w, const float* __restrict__ f2b_b,
    const float* __restrict__ conv1_w,
    float* __restrict__ a4o, float* __restrict__ G2,
    float* __restrict__ E, ushort* __restrict__ Msf)
{
    const int og = blockIdx.x, b = blockIdx.y;
    const int c = threadIdx.x;
    __shared__ float red[4];
    __shared__ float sc2[256], sa4[256], sd4[256], sg2[16];

    const float sc = s1[b*256 + c];
    const float qc = q1[b*256 + c];

    const float Ninv = 1.f / (256.f * 16000.f);
    const float Tf = 16000.f;

    float S  = blockSum256(sc, red);
    float Q  = blockSum256(qc, red);
    float mu1 = S * Ninv;
    float var1 = Q * Ninv - mu1 * mu1;
    float r1 = rsqrtf(var1 + EPSV);
    float a1 = gn_a_w[c] * r1;
    float d1 = gn_a_b[c] - mu1 * r1 * gn_a_w[c];

    float S2 = blockSum256(a1*sc + Tf*d1, red);
    float Q2 = blockSum256(a1*a1*qc + 2.f*a1*d1*sc + Tf*d1*d1, red);
    float mu2 = S2 * Ninv;
    float var2 = Q2 * Ninv - mu2 * mu2;
    float r2 = rsqrtf(var2 + EPSV);
    float wn = gn_n_w[c];
    float a2 = wn * r2 * a1;
    float d2 = wn * r2 * (d1 - mu2) + gn_n_b[c];

    const float g1v = G1[b*256 + c];
    const float b1v = B1[b*256 + c];
    float a3 = g1v * a2;
    float d3 = g1v * d2 + b1v;

    float S3 = blockSum256(a3*sc + Tf*d3, red);
    float Q3 = blockSum256(a3*a3*qc + 2.f*a3*d3*sc + Tf*d3*d3, red);
    float mu3 = S3 * Ninv;
    float var3 = Q3 * Ninv - mu3 * mu3;
    float r3 = rsqrtf(var3 + EPSV);
    float w1 = ln1_w[c];
    const float a4v = w1 * r3 * a3;
    const float d4v = w1 * r3 * (d3 - mu3) + ln1_b[c];
    sa4[c] = a4v;
    sd4[c] = d4v;
    if (og == 0) a4o[b*256 + c] = a4v;
    sc2[c] = CUE2[b*256 + c];
    __syncthreads();

    const int oi = c >> 4, l16 = c & 15;
    const int o = og*16 + oi;
    float g = 0.f, bt = 0.f, ed = 0.f;
    #pragma unroll
    for (int q = 0; q < 4; ++q) {
        const int k0 = l16*16 + q*4;
        const float4 a  = *(const float4*)(f2g_w  + o*256 + k0);
        const float4 bb = *(const float4*)(f2b_w  + o*256 + k0);
        const float4 cc = *(const float4*)(conv1_w + o*256 + k0);
        const float4 u  = *(const float4*)(&sc2[k0]);
        const float4 dd = *(const float4*)(&sd4[k0]);
        #pragma unroll
        for (int i = 0; i < 4; ++i) {
            g  = fmaf(f4c(u,i),  f4c(a,i),  g);
            bt = fmaf(f4c(u,i),  f4c(bb,i), bt);
            ed = fmaf(f4c(dd,i), f4c(cc,i), ed);
        }
    }
    #pragma unroll
    for (int m = 1; m <= 8; m <<= 1) {
        g  += __shfl_xor(g, m, 16);
        bt += __shfl_xor(bt, m, 16);
        ed += __shfl_xor(ed, m, 16);
    }
    if (l16 == 0) {
        const float G2v = fmaxf(g + f2g_b[o], 0.f) + 1.f;
        const float B2v = fmaxf(bt + f2b_b[o], 0.f);
        G2[b*128 + o] = G2v;
        E[b*128 + o]  = G2v * ed + B2v;
        sg2[oi] = G2v;
    }
    __syncthreads();
    const float av = sa4[c];
    #pragma unroll
    for (int i = 0; i < 16; ++i) {
        const int oo = og*16 + i;
        Msf[((size_t)b*128 + oo)*256 + c] = f2h(sg2[i] * conv1_w[oo*256 + c] * av);
    }
}

// ---------------------------------------------------------------------------
// Kernel C: sumsq GEMM (D=[t][o]).  4 waves = 4 o-strips of 32, TWO 64t
// tiles double-buffered; M fragments + E hoisted.  grid (125, 16).
// ---------------------------------------------------------------------------
__global__ __launch_bounds__(256) void kC_gemm(
    const ushort* __restrict__ Xp, const ushort* __restrict__ Msf,
    const float* __restrict__ E,
    float* __restrict__ q2p)
{
    const int tp = blockIdx.x, b = blockIdx.y;
    const int tid = threadIdx.x, lane = tid & 63, w = tid >> 6;
    const int sub = lane >> 4, li = lane & 15;
    const int o0 = w * 32;
    __shared__ __align__(16) ushort Bs[2][16384]; // 2 x 32 KB

    const ushort* mp = Msf + (size_t)b*32768;

    f16x8 mf[8][2];
    #pragma unroll
    for (int ks = 0; ks < 8; ++ks) {
        const int k8 = (ks >> 1)*64 + (ks & 1)*32 + 8*sub;
        #pragma unroll
        for (int fo = 0; fo < 2; ++fo)
            mf[ks][fo] = *(const f16x8*)(mp + (size_t)(o0 + fo*16 + li)*256 + k8);
    }
    float ev[2];
    #pragma unroll
    for (int fo = 0; fo < 2; ++fo)
        ev[fo] = E[b*128 + o0 + fo*16 + li];

    const ushort* src0 = Xp + ((size_t)(b*NTT + 2*tp)*4)*4096;

    #pragma unroll
    for (int m = 0; m < 8; ++m) {
        const int off = m*2048 + w*512;
        gld16(src0 + off + lane*8, &Bs[0][off]);
    }
    __syncthreads();

    float qv[2] = {0.f, 0.f};
    #pragma unroll
    for (int tile = 0; tile < 2; ++tile) {
        if (tile == 0) {
            const ushort* src1 = src0 + 16384;
            #pragma unroll
            for (int m = 0; m < 8; ++m) {
                const int off = m*2048 + w*512;
                gld16(src1 + off + lane*8, &Bs[1][off]);
            }
        }
        f32x4 acc[4][2];
        #pragma unroll
        for (int i = 0; i < 4; ++i)
            #pragma unroll
            for (int jx = 0; jx < 2; ++jx) acc[i][jx] = (f32x4){0.f,0.f,0.f,0.f};

        #pragma unroll
        for (int ks = 0; ks < 8; ++ks) {
            const int kc = ks >> 1;
            const int uo = (ks & 1)*4 + sub;
            f16x8 xf[4];
            #pragma unroll
            for (int ft = 0; ft < 4; ++ft) {
                const int tl = ft*16 + li;
                xf[ft] = *(const f16x8*)&Bs[tile][kc*4096 + tl*64 + (uo ^ (tl & 7))*8];
            }
            #pragma unroll
            for (int fo = 0; fo < 2; ++fo)
                #pragma unroll
                for (int ft = 0; ft < 4; ++ft)
                    acc[ft][fo] = __builtin_amdgcn_mfma_f32_16x16x32_f16(xf[ft], mf[ks][fo], acc[ft][fo], 0, 0, 0);
        }

        #pragma unroll
        for (int fo = 0; fo < 2; ++fo)
            #pragma unroll
            for (int ft = 0; ft < 4; ++ft)
                #pragma unroll
                for (int r = 0; r < 4; ++r) {
                    const float z = acc[ft][fo][r] + ev[fo];
                    qv[fo] += z*z;
                }
        if (tile == 0) __syncthreads();
    }

    #pragma unroll
    for (int fo = 0; fo < 2; ++fo) {
        float q = qv[fo];
        q += __shfl_xor(q, 16, 64);
        q += __shfl_xor(q, 32, 64);
        if (sub == 0)
            q2p[((size_t)b*NTB + tp)*128 + o0 + fo*16 + li] = q;
    }
}

// ---------------------------------------------------------------------------
// Kernel D2: analytic s2 + q2p reduce -> A2/AE (LDS), then
// F = [conv2*diag(A2*G2)*conv1]*diag(a4) (fp16), h = conv2.AE.
// grid (8 pg, 16 b) x 256 thr.
// ---------------------------------------------------------------------------
__global__ __launch_bounds__(256) void kD2_buildF(
    const float* __restrict__ q2p,
    const float* __restrict__ ln2_w, const float* __restrict__ ln2_b,
    const float* __restrict__ Ev,
    const float* __restrict__ a4, const float* __restrict__ G2,
    const float* __restrict__ s1,
    const float* __restrict__ conv1_w, const float* __restrict__ conv2_w,
    ushort* __restrict__ Fsf, float* __restrict__ h)
{
    const int b = blockIdx.y, pg = blockIdx.x;
    const int tid = threadIdx.x;
    __shared__ float Qs[32][128];
    __shared__ float sA2[128], sAE[128], sAS[256];
    __shared__ float rS[2], rQ[2];

    sAS[tid] = a4[b*256 + tid] * s1[b*256 + tid];
    __syncthreads();

    float s2v = 0.f, qq = 0.f;
    if (tid < 128) {
        float dot = 0.f;
        #pragma unroll 4
        for (int c4 = 0; c4 < 64; ++c4) {
            const float4 cw = *(const float4*)(conv1_w + tid*256 + c4*4);
            const float4 as = *(const float4*)(&sAS[c4*4]);
            dot = fmaf(cw.x, as.x, dot); dot = fmaf(cw.y, as.y, dot);
            dot = fmaf(cw.z, as.z, dot); dot = fmaf(cw.w, as.w, dot);
        }
        s2v = G2[b*128 + tid] * dot + 16000.f * Ev[b*128 + tid];
        for (int tb = 0; tb < NTB; ++tb)
            qq += q2p[((size_t)b*NTB + tb)*128 + tid];
        float S = s2v, Q = qq;
        #pragma unroll
        for (int off = 32; off; off >>= 1) {
            S += __shfl_down(S, off, 64);
            Q += __shfl_down(Q, off, 64);
        }
        if ((tid & 63) == 0) { rS[tid >> 6] = S; rQ[tid >> 6] = Q; }
    }
    __syncthreads();
    const float N2inv = 1.f / (128.f * 16000.f);
    const float mu  = (rS[0] + rS[1]) * N2inv;
    const float var = (rQ[0] + rQ[1]) * N2inv - mu * mu;
    const float r = rsqrtf(var + EPSV);
    if (tid < 128) {
        const float a2v = ln2_w[tid] * r;
        const float d2v = ln2_b[tid] - mu * ln2_w[tid] * r;
        sA2[tid] = a2v;
        sAE[tid] = a2v * Ev[b*128 + tid] + d2v;
    }
    __syncthreads();

    #pragma unroll
    for (int k = 0; k < 16; ++k) {
        const int idx = tid + k*256;
        const int p = idx >> 7, o = idx & 127;
        Qs[p][o] = conv2_w[(pg*32 + p)*128 + o] * sA2[o] * G2[b*128 + o];
    }
    __syncthreads();
    float acc[32];
    #pragma unroll
    for (int p = 0; p < 32; ++p) acc[p] = 0.f;
    for (int o = 0; o < 128; ++o) {
        const float mv = conv1_w[o*256 + tid];
        #pragma unroll
        for (int p = 0; p < 32; ++p) acc[p] = fmaf(Qs[p][o], mv, acc[p]);
    }
    const float a = a4[b*256 + tid];
    #pragma unroll
    for (int p = 0; p < 32; ++p) {
        const size_t idx = ((size_t)b*256 + pg*32 + p)*256 + tid;
        Fsf[idx] = f2h(acc[p] * a);
    }
    if (tid < 32) {
        const int p = pg*32 + tid;
        float hv = 0.f;
        for (int o = 0; o < 128; ++o)
            hv += conv2_w[p*128 + o] * sAE[o];
        h[b*256 + p] = hv;
    }
}

// ---------------------------------------------------------------------------
// Kernel E: out = F x + h (D=[t][o]).  Block 128o, TWO 64-t tiles with
// double-buffered staging; F fragments hoisted to VGPRs.
// grid (125, 32): b=y>>1, obase=(y&1)*128.
// ---------------------------------------------------------------------------
__global__ __launch_bounds__(256) void kE_gemm(
    const ushort* __restrict__ Xp, const ushort* __restrict__ Fsf,
    const float* __restrict__ h, float* __restrict__ out)
{
    const int txp = blockIdx.x;
    const int b = blockIdx.y >> 1;
    const int o_base = (blockIdx.y & 1) * 128;
    const int tid = threadIdx.x, lane = tid & 63, w = tid >> 6;
    const int sub = lane >> 4, li = lane & 15;
    const int o0 = o_base + w * 32;
    __shared__ __align__(16) ushort Bs[2][16384]; // 2 x 32 KB

    const ushort* fp = Fsf + (size_t)b*65536;

    f16x8 ff[8][2];
    #pragma unroll
    for (int ks = 0; ks < 8; ++ks) {
        const int k8 = (ks >> 1)*64 + (ks & 1)*32 + 8*sub;
        #pragma unroll
        for (int fo = 0; fo < 2; ++fo)
            ff[ks][fo] = *(const f16x8*)(fp + (size_t)(o0 + fo*16 + li)*256 + k8);
    }
    float hv[2];
    #pragma unroll
    for (int fo = 0; fo < 2; ++fo)
        hv[fo] = h[b*256 + o0 + fo*16 + li];

    const ushort* src0 = Xp + ((size_t)(b*NTT + 2*txp)*4)*4096;

    #pragma unroll
    for (int m = 0; m < 8; ++m) {
        const int off = m*2048 + w*512;
        gld16(src0 + off + lane*8, &Bs[0][off]);
    }
    __syncthreads();

    #pragma unroll
    for (int tile = 0; tile < 2; ++tile) {
        if (tile == 0) {
            const ushort* src1 = src0 + 16384;
            #pragma unroll
            for (int m = 0; m < 8; ++m) {
                const int off = m*2048 + w*512;
                gld16(src1 + off + lane*8, &Bs[1][off]);
            }
        }
        f32x4 acc[4][2];
        #pragma unroll
        for (int i = 0; i < 4; ++i)
            #pragma unroll
            for (int jx = 0; jx < 2; ++jx) acc[i][jx] = (f32x4){0.f,0.f,0.f,0.f};

        #pragma unroll
        for (int ks = 0; ks < 8; ++ks) {
            const int kc = ks >> 1;
            const int uo = (ks & 1)*4 + sub;
            f16x8 xf[4];
            #pragma unroll
            for (int ft = 0; ft < 4; ++ft) {
                const int tl = ft*16 + li;
                xf[ft] = *(const f16x8*)&Bs[tile][kc*4096 + tl*64 + (uo ^ (tl & 7))*8];
            }
            #pragma unroll
            for (int fo = 0; fo < 2; ++fo)
                #pragma unroll
                for (int ft = 0; ft < 4; ++ft)
                    acc[ft][fo] = __builtin_amdgcn_mfma_f32_16x16x32_f16(xf[ft], ff[ks][fo], acc[ft][fo], 0, 0, 0);
        }

        const int t0 = (2*txp + tile)*64;
        #pragma unroll
        for (int fo = 0; fo < 2; ++fo) {
            const int o = o0 + fo*16 + li;
            float* obase = out + ((size_t)(b*256 + o))*T_LEN + t0;
            #pragma unroll
            for (int ft = 0; ft < 4; ++ft) {
                f32x4 v;
                v[0] = acc[ft][fo][0] + hv[fo];
                v[1] = acc[ft][fo][1] + hv[fo];
                v[2] = acc[ft][fo][2] + hv[fo];
                v[3] = acc[ft][fo][3] + hv[fo];
                __builtin_nontemporal_store(v, (f32x4*)(obase + ft*16 + sub*4));
            }
        }
        if (tile == 0) __syncthreads();
    }
}

// ---------------------------------------------------------------------------
extern "C" void kernel_launch(void* const* d_in, const int* in_sizes, int n_in,
                              void* d_out, int out_size, void* d_ws, size_t ws_size,
                              hipStream_t stream)
{
    const float* x       = (const float*)d_in[0];
    const float* cue     = (const float*)d_in[1];
    const float* gn_a_w  = (const float*)d_in[2];
    const float* gn_a_b  = (const float*)d_in[3];
    const float* gn_n_w  = (const float*)d_in[4];
    const float* gn_n_b  = (const float*)d_in[5];
    const float* f1g_w   = (const float*)d_in[6];
    const float* f1g_b   = (const float*)d_in[7];
    const float* f1b_w   = (const float*)d_in[8];
    const float* f1b_b   = (const float*)d_in[9];
    const float* ln1_w   = (const float*)d_in[10];
    const float* ln1_b   = (const float*)d_in[11];
    const float* conv1_w = (const float*)d_in[12];
    const float* cds_w   = (const float*)d_in[13];
    const float* f2g_w   = (const float*)d_in[14];
    const float* f2g_b   = (const float*)d_in[15];
    const float* f2b_w   = (const float*)d_in[16];
    const float* f2b_b   = (const float*)d_in[17];
    const float* ln2_w   = (const float*)d_in[18];
    const float* ln2_b   = (const float*)d_in[19];
    const float* conv2_w = (const float*)d_in[20];
    float* out = (float*)d_out;

    float* ws = (float*)d_ws;
    float*  sp   = ws;                       // 1,024,000
    float*  qp   = ws + 1024000;             // 1,024,000
    float*  G1   = ws + 2048000;             // 4,096
    float*  B1   = ws + 2052096;             // 4,096
    float*  CUE2 = ws + 2056192;             // 4,096
    float*  G2   = ws + 2060288;             // 2,048
    float*  a4   = ws + 2062336;             // 4,096
    float*  E    = ws + 2066432;             // 2,048
    float*  h    = ws + 2068480;             // 4,096
    float*  s1   = ws + 2072576;             // 4,096
    float*  q1   = ws + 2076672;             // 4,096
    float*  q2p  = ws + 2080768;             // 256,000
    ushort* Msf  = (ushort*)(ws + 2336768);  // 524,288 ush (262,144 f)
    ushort* Fsf  = (ushort*)(ws + 2598912);  // 1,048,576 ush (524,288 f)
    ushort* Xp   = (ushort*)(ws + 3123200);  // 65,536,000 ush
    // total ~ 35,891,200 floats ~= 143.6 MB

    kP1F<<<256 + NTT*NB, 256, 0, stream>>>(x, Xp, sp, qp,
        cue, f1g_w, f1g_b, f1b_w, f1b_b, cds_w, G1, B1, CUE2);

    kR_reduce<<<dim3(8, NB), 256, 0, stream>>>(sp, qp, s1, q1);

    kM2F<<<dim3(8, NB), 256, 0, stream>>>(s1, q1,
        gn_a_w, gn_a_b, gn_n_w, gn_n_b, G1, B1, ln1_w, ln1_b,
        CUE2, f2g_w, f2g_b, f2b_w, f2b_b, conv1_w,
        a4, G2, E, Msf);

    kC_gemm<<<dim3(NTB, NB), 256, 0, stream>>>(Xp, Msf, E, q2p);

    kD2_buildF<<<dim3(8, NB), 256, 0, stream>>>(q2p, ln2_w, ln2_b, E,
                                                a4, G2, s1, conv1_w, conv2_w,
                                                Fsf, h);

    kE_gemm<<<dim3(NTB, NB*2), 256, 0, stream>>>(Xp, Fsf, h, out);
}